// Round 2
// baseline (35960.284 us; speedup 1.0000x reference)
//
#include <hip/hip_runtime.h>

typedef _Float16 f16;
typedef _Float16 f16x8 __attribute__((ext_vector_type(8)));
typedef float f32x4 __attribute__((ext_vector_type(4)));

#define NSTEPS 512
#define NBATCH 256
#define HID 256
#define PITCH 264          // f16 row pitch for 16-row h tiles (mult of 8; 528B stride -> 2-way LDS aliasing only, free)
#define XPITCH 40          // layer-0 x tile pitch (32 cols used)
#define THREADS 1024
#define NWG 16

#define WPACK_OFF ((size_t)1024)
#define WPACK_ELEMS ((size_t)64*16*64*8)        // f16 elems per layer
#define WPACK_SZB (WPACK_ELEMS*2)               // 1 MiB per layer
#define WS_NEEDED (WPACK_OFF + 3*WPACK_SZB)

__device__ __forceinline__ float sigm(float x){ return 1.f/(1.f+__expf(-x)); }
__device__ __forceinline__ float tanh_f(float x){ return 1.f - 2.f/(1.f+__expf(2.f*x)); }

// weight packing: [layer][nt(64)][kb(16)][lane(64)][e(8)] f16
// B-fragment for mfma_f32_16x16x32_f16: col n = nt*16 + (lane&15), k = kb*32 + (lane>>4)*8 + e.
// k<256 -> w_hh[n][k]; k>=256 -> w_ih[n][k-256] (0-padded past in_dim).
__global__ __launch_bounds__(256) void pack_weights(
    const float* __restrict__ wih0, const float* __restrict__ whh0,
    const float* __restrict__ wih1, const float* __restrict__ whh1,
    const float* __restrict__ wih2, const float* __restrict__ whh2,
    unsigned char* __restrict__ ws)
{
  int gid = blockIdx.x*256 + threadIdx.x;
  if (gid >= 3*64*16*64) return;
  int lane  = gid & 63;
  int kb    = (gid>>6) & 15;
  int nt    = (gid>>10) & 63;
  int layer = gid>>16;
  const float* whh = (layer==0)?whh0:((layer==1)?whh1:whh2);
  const float* wih = (layer==0)?wih0:((layer==1)?wih1:wih2);
  int indim = (layer==0)?12:256;
  int n  = nt*16 + (lane&15);
  int k0 = kb*32 + (lane>>4)*8;
  f16x8 v;
  #pragma unroll
  for (int e=0;e<8;++e){
    int k = k0+e;
    float x;
    if (k < HID) x = whh[n*HID + k];
    else { int ki = k-HID; x = (ki<indim)? wih[n*indim+ki] : 0.f; }
    v[e] = (f16)x;
  }
  f16* dst = (f16*)(ws + WPACK_OFF) + (size_t)layer*WPACK_ELEMS
           + ((size_t)(nt*16+kb)*64 + lane)*8;
  *(f16x8*)dst = v;
}

// One LSTM layer step for 16 batch rows. Wave w owns column-tile ct=w for ALL
// four gates (nt = G*16 + w) -> the cell is computed entirely in registers.
template<int KB, bool IS_LAST>
__device__ __forceinline__ void layer_step(
    const f16* __restrict__ hbuf,   // h_{t-1}, pitch PITCH, 16 rows x 256
    const f16* __restrict__ xbuf,   // x_t, pitch XP
    int XP,
    f16* __restrict__ hdst,         // h_t out (other parity buffer)
    const f16* __restrict__ wp,     // packed weights for this layer
    const float* __restrict__ bias, // [4] this lane's column bias per gate
    float* __restrict__ cst,        // [4] c-state for this lane's 4 rows
    int w, int lane, int c16, int r0,
    float wl, float (*Lout)[16])
{
  f32x4 acc[4];
  #pragma unroll
  for (int G=0;G<4;++G){ f32x4 z={0.f,0.f,0.f,0.f}; acc[G]=z; }
  #pragma unroll
  for (int kb=0; kb<KB; ++kb){
    const f16* ap = (kb<8) ? &hbuf[c16*PITCH + kb*32 + (lane>>4)*8]
                           : &xbuf[c16*XP + (kb-8)*32 + (lane>>4)*8];
    f16x8 a = *(const f16x8*)ap;
    #pragma unroll
    for (int G=0; G<4; ++G){
      int nt = G*16 + w;
      f16x8 b = *(const f16x8*)(wp + ((size_t)(nt*16+kb)*64 + lane)*8);
      acc[G] = __builtin_amdgcn_mfma_f32_16x16x32_f16(a, b, acc[G], 0,0,0);
    }
  }
  float lp[4];
  #pragma unroll
  for (int q=0;q<4;++q){
    float gi = sigm  (acc[0][q]+bias[0]);
    float gf = sigm  (acc[1][q]+bias[1]);
    float gg = tanh_f(acc[2][q]+bias[2]);
    float go = sigm  (acc[3][q]+bias[3]);
    float cv = gf*cst[q] + gi*gg; cst[q]=cv;
    float h  = go*tanh_f(cv);
    hdst[(r0+q)*PITCH + w*16 + c16] = (f16)h;
    lp[q] = h*wl;
  }
  if (IS_LAST){
    #pragma unroll
    for (int q=0;q<4;++q){
      #pragma unroll
      for (int off=1; off<16; off<<=1) lp[q] += __shfl_xor(lp[q], off);
    }
    if (c16==0){
      #pragma unroll
      for (int q=0;q<4;++q) Lout[r0+q][w] = lp[q];
    }
  }
}

// 16 WGs x 1024 threads. WG = 16 batch rows, all 3 layers + linear head fused.
// No inter-WG communication at all.
__global__ __launch_bounds__(THREADS, 4) void lstm_fused(
    const float* __restrict__ input,
    const float* __restrict__ bih0, const float* __restrict__ bhh0,
    const float* __restrict__ bih1, const float* __restrict__ bhh1,
    const float* __restrict__ bih2, const float* __restrict__ bhh2,
    const float* __restrict__ wlin, const float* __restrict__ blin,
    const unsigned char* __restrict__ ws, float* __restrict__ out)
{
  __shared__ __attribute__((aligned(16))) f16 Ah[3][2][16*PITCH]; // h double-buffered per layer
  __shared__ __attribute__((aligned(16))) f16 Ax0[16*XPITCH];     // layer-0 x (12 of 32 cols)
  __shared__ float Lout[16][16];                                  // linear head partials

  const int tid  = threadIdx.x;
  const int w    = tid >> 6;          // 16 waves
  const int lane = tid & 63;
  const int c16  = lane & 15;
  const int r0   = (lane >> 4) * 4;
  const int rowsBase = blockIdx.x * 16;

  const f16* wp0 = (const f16*)(ws + WPACK_OFF);
  const f16* wp1 = wp0 + WPACK_ELEMS;
  const f16* wp2 = wp0 + 2*WPACK_ELEMS;

  const float* BIH[3] = {bih0,bih1,bih2};
  const float* BHH[3] = {bhh0,bhh1,bhh2};
  float bias[3][4], cst[3][4];
  #pragma unroll
  for (int l=0;l<3;++l)
    #pragma unroll
    for (int G=0;G<4;++G){
      int n = G*256 + w*16 + c16;
      bias[l][G] = BIH[l][n] + BHH[l][n];
      cst[l][G]  = 0.f;   // reused as [q] below; init all
    }
  // cst is indexed [layer][q]; zero-init done above (same 3x4 storage)
  const float wl = wlin[w*16 + c16];
  const float bl = blin[0];

  for (int i=tid; i<3*2*16*PITCH; i+=THREADS) ((f16*)Ah)[i] = (f16)0.f;
  for (int i=tid; i<16*XPITCH;   i+=THREADS) Ax0[i] = (f16)0.f;
  __syncthreads();
  if (tid < 192){
    int rr = tid/12, ii = tid - rr*12;
    Ax0[rr*XPITCH + ii] = (f16)input[((size_t)0*NBATCH + rowsBase + rr)*12 + ii];
  }
  __syncthreads();

  for (int t=0; t<NSTEPS; ++t){
    const int pc = t & 1, pn = pc ^ 1;

    // emit out(t-1) from Lout written in phase 2 of step t-1 (barrier-separated)
    if (t > 0 && tid < 16){
      float s = bl;
      #pragma unroll
      for (int k=0;k<16;++k) s += Lout[tid][k];
      out[(size_t)(t-1)*NBATCH + rowsBase + tid] = s;
    }

    // phase 0: layer 0 (x is 12 dims -> only 9 K-blocks)
    layer_step<9,false>(Ah[0][pc], Ax0, XPITCH, Ah[0][pn],
                        wp0, bias[0], cst[0], w, lane, c16, r0, 0.f, Lout);
    __syncthreads();
    // phase 1: layer 1 (x = h^0_t, read directly from Ah[0][pn])
    layer_step<16,false>(Ah[1][pc], Ah[0][pn], PITCH, Ah[1][pn],
                         wp1, bias[1], cst[1], w, lane, c16, r0, 0.f, Lout);
    __syncthreads();
    // phase 2: layer 2 + fused linear head
    layer_step<16,true>(Ah[2][pc], Ah[1][pn], PITCH, Ah[2][pn],
                        wp2, bias[2], cst[2], w, lane, c16, r0, wl, Lout);
    // stage next step's input (Ax0 only read in phase 0, barrier-separated)
    if (t+1 < NSTEPS && tid < 192){
      int rr = tid/12, ii = tid - rr*12;
      Ax0[rr*XPITCH + ii] = (f16)input[((size_t)(t+1)*NBATCH + rowsBase + rr)*12 + ii];
    }
    __syncthreads();
  }

  if (tid < 16){
    float s = bl;
    #pragma unroll
    for (int k=0;k<16;++k) s += Lout[tid][k];
    out[(size_t)(NSTEPS-1)*NBATCH + rowsBase + tid] = s;
  }
}

extern "C" void kernel_launch(void* const* d_in, const int* in_sizes, int n_in,
                              void* d_out, int out_size, void* d_ws, size_t ws_size,
                              hipStream_t stream)
{
  const float* input=(const float*)d_in[0];
  const float* wih0 =(const float*)d_in[1];
  const float* whh0 =(const float*)d_in[2];
  const float* bih0 =(const float*)d_in[3];
  const float* bhh0 =(const float*)d_in[4];
  const float* wih1 =(const float*)d_in[5];
  const float* whh1 =(const float*)d_in[6];
  const float* bih1 =(const float*)d_in[7];
  const float* bhh1 =(const float*)d_in[8];
  const float* wih2 =(const float*)d_in[9];
  const float* whh2 =(const float*)d_in[10];
  const float* bih2 =(const float*)d_in[11];
  const float* bhh2 =(const float*)d_in[12];
  const float* wlin =(const float*)d_in[13];
  const float* blin =(const float*)d_in[14];
  unsigned char* ws = (unsigned char*)d_ws;
  if (ws_size < WS_NEEDED) return;   // ~3.2 MB needed

  hipLaunchKernelGGL(pack_weights, dim3(768), dim3(256), 0, stream,
                     wih0,whh0,wih1,whh1,wih2,whh2, ws);
  hipLaunchKernelGGL(lstm_fused, dim3(NWG), dim3(THREADS), 0, stream,
                     input, bih0,bhh0,bih1,bhh1,bih2,bhh2, wlin, blin,
                     ws, (float*)d_out);
}